// Round 1
// baseline (984.880 us; speedup 1.0000x reference)
//
#include <hip/hip_runtime.h>

// HierarchicalLTI2: 32-layer cascade of 64-dim LTI blocks, T=8192.
// Per-layer FIR truncation at J=16 taps, each layer = GEMM (M=8192,N=64,K=1024)
// via implicit im2col, f16 MFMA fp32-acc.
// R4: single persistent cooperative kernel — build/castK/32 stages/y_final fused,
// 37 global barriers (~1-2us) replace 37 kernel launch boundaries (~5-6us each).

#define LYR 32
#define NO  64
#define TSEQ 8192
#define JT  16
#define KD  (JT*NO)              // 1024
#define PROWS (TSEQ+JT)          // 8208
#define PBUF ((size_t)PROWS*NO)  // 525312 elements (f16)
#define NB  256                  // persistent grid (1 block/CU)

typedef _Float16 h16;
typedef _Float16 h16x8 __attribute__((ext_vector_type(8)));
typedef float    f32x4 __attribute__((ext_vector_type(4)));

// ---- device-scope grid barrier (cumulative counter, no reset) --------------
__device__ __forceinline__ void gbar(unsigned* cnt, unsigned target)
{
    __syncthreads();                       // all block stores issued (vmcnt drained)
    if (threadIdx.x == 0) {
        __threadfence();                   // release: L2 writeback for cross-XCD
        atomicAdd(cnt, 1u);
        while (__hip_atomic_load(cnt, __ATOMIC_RELAXED, __HIP_MEMORY_SCOPE_AGENT) < target)
            __builtin_amdgcn_s_sleep(2);
        __threadfence();                   // acquire: invalidate stale L1/L2
    }
    __syncthreads();
}

// ---- prep1: zero pads (all 33 buffers), cast u + C, seed K_0, zero cnt -----
__global__ __launch_bounds__(256) void prep1(
    const float* __restrict__ u, const float* __restrict__ B0,
    const float* __restrict__ Bl, const float* __restrict__ Cst,
    h16* __restrict__ pall, h16* __restrict__ ccast, float* __restrict__ kf32,
    unsigned* __restrict__ cnt)
{
    if (blockIdx.x == 0 && threadIdx.x == 0) *cnt = 0u;
    int idx = blockIdx.x*256 + threadIdx.x;
    const int n_pad0 = JT*NO;            // 1024
    const int n_u    = TSEQ*NO;          // 524288
    const int n_c    = LYR*NO*NO;        // 131072
    const int n_k    = LYR*NO*NO;        // 131072
    const int n_zp   = 32*JT*NO;         // 32768 (pads of buffers 1..32)
    int total = n_pad0 + n_u + n_c + n_k + n_zp;
    for (; idx < total; idx += gridDim.x*256) {
        int e = idx;
        if (e < n_pad0) { pall[e] = (h16)0.f; continue; }
        e -= n_pad0;
        if (e < n_u) { pall[n_pad0 + e] = (h16)u[e]; continue; }
        e -= n_u;
        if (e < n_c) { ccast[e] = (h16)Cst[e]; continue; }
        e -= n_c;
        if (e < n_k) {
            int i = e >> 12;
            int r = e & 4095;
            kf32[((size_t)i*JT)*4096 + r] = (i == 0) ? B0[r] : Bl[e - 4096];
            continue;
        }
        e -= n_k;
        int b = e >> 10;                 // buffer-1 index 0..31
        int off = e & 1023;
        pall[(size_t)(b+1)*PBUF + off] = (h16)0.f;
    }
}

// ---- build phase body: K_{h+q} = A^h * K_q ; A^{2h} = A^h * A^h ------------
__device__ __forceinline__ void build_body(
    const float* __restrict__ Ast, float* __restrict__ kf32,
    float* __restrict__ apow, int s, int bid, int tid, char* smraw)
{
    int h = 1 << s;
    int extra = (s < 3) ? 1 : 0;
    int slots = h + extra;
    int layer = bid / slots;
    int q     = bid % slots;
    const float* X = (s == 0) ? (Ast + (size_t)layer*4096)
                              : (apow + ((size_t)layer*4 + (s-1))*4096);
    const float* Yop;
    float* Z;
    if (q < h) { Yop = kf32 + ((size_t)layer*JT + q)*4096;
                 Z   = kf32 + ((size_t)layer*JT + h + q)*4096; }
    else       { Yop = X;
                 Z   = apow + ((size_t)layer*4 + s)*4096; }

    float* lx = (float*)smraw;                 // 64x68 f32
    float* ly = (float*)(smraw + 64*68*4);     // 64x68 f32
    for (int e = tid; e < 4096; e += 256) {
        int r = e >> 6, c = e & 63;
        lx[r*68 + c] = X[e];
        ly[r*68 + c] = Yop[e];
    }
    __syncthreads();
    int r0 = (tid >> 4) << 2;
    int c0 = (tid & 15) << 2;
    float acc[4][4] = {};
    for (int k = 0; k < 64; k++) {
        float a0 = lx[(r0+0)*68 + k];
        float a1 = lx[(r0+1)*68 + k];
        float a2 = lx[(r0+2)*68 + k];
        float a3 = lx[(r0+3)*68 + k];
        f32x4 bv = *(const f32x4*)&ly[k*68 + c0];
        #pragma unroll
        for (int j = 0; j < 4; j++) {
            acc[0][j] += a0*bv[j]; acc[1][j] += a1*bv[j];
            acc[2][j] += a2*bv[j]; acc[3][j] += a3*bv[j];
        }
    }
    #pragma unroll
    for (int i2 = 0; i2 < 4; i2++) {
        f32x4 o; o[0]=acc[i2][0]; o[1]=acc[i2][1]; o[2]=acc[i2][2]; o[3]=acc[i2][3];
        *(f32x4*)&Z[(size_t)(r0+i2)*64 + c0] = o;
    }
}

// ---- stage body: 32-row tiles, split-K4, 8-half-step chains ----------------
__device__ __forceinline__ void stage_body(
    const h16* __restrict__ pin, h16* __restrict__ pout,
    const h16* __restrict__ kb, int bid, int tid, char* smraw)
{
    h16*   win = (h16*)smraw;                         // 48 x 72 h16 = 6,912 B
    float* red = (float*)smraw;                       // 2 x 32x68 f32
    size_t t0 = (size_t)bid * 32;
    for (int e = tid; e < 48*8; e += 256) {
        int rr = e >> 3, cc = e & 7;
        *(int4*)&win[rr*72 + cc*8] = *(const int4*)&pin[(t0 + rr)*64 + cc*8];
    }
    __syncthreads();
    int wv = tid >> 6, lane = tid & 63, r = lane & 15, q = lane >> 4;
    const h16* abase = &win[(r + wv*4)*72 + q*8];
    const h16* bbase = kb + (size_t)r*KD + wv*256 + q*8;
#define LDA(s, ls) (*(const h16x8*)(abase + ((s)*16 + ((ls)>>1))*72 + ((ls)&1)*32))
#define LDB(c, ls) (*(const h16x8*)(bbase + (c)*(16*KD) + (ls)*32))
    f32x4 acc[2][4] = {};
    h16x8 a0[2], b0[4], a1[2], b1[4];
    #pragma unroll
    for (int s = 0; s < 2; s++) { a0[s]=LDA(s,0); a1[s]=LDA(s,1); }
    #pragma unroll
    for (int c = 0; c < 4; c++) { b0[c]=LDB(c,0); b1[c]=LDB(c,1); }
    #pragma unroll 1
    for (int h2 = 0; h2 < 4; h2++) {
        int pE = 2*h2 + 2; pE = pE > 7 ? 7 : pE;
        int pO = 2*h2 + 3; pO = pO > 7 ? 7 : pO;
        h16x8 ca[2], cb[4];
        #pragma unroll
        for (int s = 0; s < 2; s++) ca[s] = a0[s];
        #pragma unroll
        for (int c = 0; c < 4; c++) cb[c] = b0[c];
        #pragma unroll
        for (int s = 0; s < 2; s++) a0[s] = LDA(s, pE);
        #pragma unroll
        for (int c = 0; c < 4; c++) b0[c] = LDB(c, pE);
        #pragma unroll
        for (int s = 0; s < 2; s++)
            #pragma unroll
            for (int c = 0; c < 4; c++)
                acc[s][c] = __builtin_amdgcn_mfma_f32_16x16x32_f16(ca[s], cb[c], acc[s][c], 0,0,0);
        #pragma unroll
        for (int s = 0; s < 2; s++) ca[s] = a1[s];
        #pragma unroll
        for (int c = 0; c < 4; c++) cb[c] = b1[c];
        #pragma unroll
        for (int s = 0; s < 2; s++) a1[s] = LDA(s, pO);
        #pragma unroll
        for (int c = 0; c < 4; c++) b1[c] = LDB(c, pO);
        #pragma unroll
        for (int s = 0; s < 2; s++)
            #pragma unroll
            for (int c = 0; c < 4; c++)
                acc[s][c] = __builtin_amdgcn_mfma_f32_16x16x32_f16(ca[s], cb[c], acc[s][c], 0,0,0);
    }
#undef LDA
#undef LDB
    __syncthreads();                 // win dead; red may overwrite
    if (wv >= 2) {
        float* myred = red + (size_t)(wv-2)*(32*68);
        #pragma unroll
        for (int s = 0; s < 2; s++)
            #pragma unroll
            for (int c = 0; c < 4; c++)
                #pragma unroll
                for (int g = 0; g < 4; g++)
                    myred[(s*16 + q*4 + g)*68 + c*16 + r] = acc[s][c][g];
    }
    __syncthreads();
    if (wv < 2) {
        float* myred = red + (size_t)wv*(32*68);
        #pragma unroll
        for (int s = 0; s < 2; s++)
            #pragma unroll
            for (int c = 0; c < 4; c++)
                #pragma unroll
                for (int g = 0; g < 4; g++)
                    myred[(s*16 + q*4 + g)*68 + c*16 + r] += acc[s][c][g];
    }
    __syncthreads();
    int orow = tid >> 3, cb2 = (tid & 7) << 3;
    f32x4 u0 = *(const f32x4*)&red[orow*68 + cb2];
    f32x4 u1 = *(const f32x4*)&red[orow*68 + cb2 + 4];
    f32x4 v0 = *(const f32x4*)&red[32*68 + orow*68 + cb2];
    f32x4 v1 = *(const f32x4*)&red[32*68 + orow*68 + cb2 + 4];
    u0 += v0; u1 += v1;
    h16 ov[8];
    #pragma unroll
    for (int j = 0; j < 4; j++) { ov[j] = (h16)u0[j]; ov[4+j] = (h16)u1[j]; }
    *(int4*)&pout[(JT + t0 + orow)*64 + cb2] = *(int4*)&ov[0];
}

// ---- y_final body: Y = sum_i X^(i) C_i^T, 32-row tiles, split-K4 -----------
__device__ __forceinline__ void yfinal_body(
    const h16* __restrict__ pall, const h16* __restrict__ ccast,
    float* __restrict__ out, int bid, int tid, char* smraw)
{
    float* red = (float*)smraw;      // 2 x 32x68 f32
    size_t t0 = (size_t)bid * 32;
    int wv = tid >> 6, lane = tid & 63, r = lane & 15, q = lane >> 4;
    const h16* abase = pall + (size_t)(wv*8 + 1)*PBUF + (JT + t0 + r)*64 + q*8;
    const h16* bbase = ccast + (size_t)(wv*8)*4096 + (size_t)r*64 + q*8;
#define LDA2(s, ls) (*(const h16x8*)(abase + (size_t)((ls)>>1)*PBUF + (s)*(16*64) + ((ls)&1)*32))
#define LDB2(c, ls) (*(const h16x8*)(bbase + ((ls)>>1)*4096 + (c)*(16*64) + ((ls)&1)*32))
    f32x4 acc[2][4] = {};
    h16x8 a0[2], b0[4], a1[2], b1[4];
    #pragma unroll
    for (int s = 0; s < 2; s++) { a0[s]=LDA2(s,0); a1[s]=LDA2(s,1); }
    #pragma unroll
    for (int c = 0; c < 4; c++) { b0[c]=LDB2(c,0); b1[c]=LDB2(c,1); }
    #pragma unroll 1
    for (int h2 = 0; h2 < 8; h2++) {
        int pE = 2*h2 + 2; pE = pE > 15 ? 15 : pE;
        int pO = 2*h2 + 3; pO = pO > 15 ? 15 : pO;
        h16x8 ca[2], cb[4];
        #pragma unroll
        for (int s = 0; s < 2; s++) ca[s] = a0[s];
        #pragma unroll
        for (int c = 0; c < 4; c++) cb[c] = b0[c];
        #pragma unroll
        for (int s = 0; s < 2; s++) a0[s] = LDA2(s, pE);
        #pragma unroll
        for (int c = 0; c < 4; c++) b0[c] = LDB2(c, pE);
        #pragma unroll
        for (int s = 0; s < 2; s++)
            #pragma unroll
            for (int c = 0; c < 4; c++)
                acc[s][c] = __builtin_amdgcn_mfma_f32_16x16x32_f16(ca[s], cb[c], acc[s][c], 0,0,0);
        #pragma unroll
        for (int s = 0; s < 2; s++) ca[s] = a1[s];
        #pragma unroll
        for (int c = 0; c < 4; c++) cb[c] = b1[c];
        #pragma unroll
        for (int s = 0; s < 2; s++) a1[s] = LDA2(s, pO);
        #pragma unroll
        for (int c = 0; c < 4; c++) b1[c] = LDB2(c, pO);
        #pragma unroll
        for (int s = 0; s < 2; s++)
            #pragma unroll
            for (int c = 0; c < 4; c++)
                acc[s][c] = __builtin_amdgcn_mfma_f32_16x16x32_f16(ca[s], cb[c], acc[s][c], 0,0,0);
    }
#undef LDA2
#undef LDB2
    if (wv >= 2) {
        float* myred = red + (size_t)(wv-2)*(32*68);
        #pragma unroll
        for (int s = 0; s < 2; s++)
            #pragma unroll
            for (int c = 0; c < 4; c++)
                #pragma unroll
                for (int g = 0; g < 4; g++)
                    myred[(s*16 + q*4 + g)*68 + c*16 + r] = acc[s][c][g];
    }
    __syncthreads();
    if (wv < 2) {
        float* myred = red + (size_t)wv*(32*68);
        #pragma unroll
        for (int s = 0; s < 2; s++)
            #pragma unroll
            for (int c = 0; c < 4; c++)
                #pragma unroll
                for (int g = 0; g < 4; g++)
                    myred[(s*16 + q*4 + g)*68 + c*16 + r] += acc[s][c][g];
    }
    __syncthreads();
    int orow = tid >> 3, cb2 = (tid & 7) << 3;
    f32x4 u0 = *(const f32x4*)&red[orow*68 + cb2];
    f32x4 u1 = *(const f32x4*)&red[orow*68 + cb2 + 4];
    f32x4 v0 = *(const f32x4*)&red[32*68 + orow*68 + cb2];
    f32x4 v1 = *(const f32x4*)&red[32*68 + orow*68 + cb2 + 4];
    u0 += v0; u1 += v1;
    size_t obase = (t0 + orow)*64 + cb2;
    *(f32x4*)&out[obase]     = u0;
    *(f32x4*)&out[obase + 4] = u1;
}

// ---- the persistent mega-kernel: build x4, castK, 32 stages, y_final -------
__global__ __launch_bounds__(256, 2) void mega(
    const float* __restrict__ Ast, float* __restrict__ kf32,
    float* __restrict__ apow, h16* __restrict__ kt,
    h16* __restrict__ pall, const h16* __restrict__ ccast,
    float* __restrict__ out, unsigned* __restrict__ cnt)
{
    __shared__ __align__(16) char smraw[64*68*4*2];   // 34,816 B (union of all phases)
    const int tid = threadIdx.x;
    const int bid = blockIdx.x;
    unsigned tgt = 0;

    // ---- build: K_{h+q} = A^h * K_q ; A^{2h} = A^h*A^h --------------------
    #pragma unroll 1
    for (int s = 0; s < 4; s++) {
        int slots = (1 << s) + (s < 3 ? 1 : 0);
        if (bid < 32*slots)
            build_body(Ast, kf32, apow, s, bid, tid, smraw);
        tgt += NB; gbar(cnt, tgt);
    }

    // ---- castK: Kf32[i][j][n][m] -> f16 KbufT[i][n][(15-j)*64+m] ----------
    {
        const int total = LYR*NO*KD;     // 2,097,152
        #pragma unroll 1
        for (int idx = bid*256 + tid; idx < total; idx += NB*256) {
            int i   = idx >> 16;
            int rem = idx & 65535;
            int n   = rem >> 10;
            int kap = rem & 1023;
            int jp  = kap >> 6, m = kap & 63;
            int j   = JT-1-jp;
            kt[idx] = (h16)kf32[(((size_t)i*JT + j)*64 + n)*64 + m];
        }
        tgt += NB; gbar(cnt, tgt);
    }

    // ---- 32 cascade stages ------------------------------------------------
    #pragma unroll 1
    for (int i = 0; i < LYR; i++) {
        stage_body(pall + (size_t)i*PBUF, pall + (size_t)(i+1)*PBUF,
                   kt + (size_t)i*NO*KD, bid, tid, smraw);
        tgt += NB; gbar(cnt, tgt);
    }

    // ---- y_final ----------------------------------------------------------
    yfinal_body(pall, ccast, out, bid, tid, smraw);
}

extern "C" void kernel_launch(void* const* d_in, const int* in_sizes, int n_in,
                              void* d_out, int out_size, void* d_ws, size_t ws_size,
                              hipStream_t stream)
{
    const float* u   = (const float*)d_in[0];
    const float* Ast = (const float*)d_in[1];
    const float* B0  = (const float*)d_in[2];
    const float* Bl  = (const float*)d_in[3];
    const float* Cst = (const float*)d_in[4];
    float* outp = (float*)d_out;
    (void)in_sizes; (void)n_in; (void)out_size; (void)ws_size;

    char* ws = (char*)d_ws;
    const size_t PBUF_BYTES = PBUF*sizeof(h16);            // 1,050,624
    h16*   pall  = (h16*)ws;                               // 33 buffers
    h16*   ccast = (h16*)(ws + 33*PBUF_BYTES);             // 256 KiB
    h16*   kt    = (h16*)(ws + 33*PBUF_BYTES + 262144);    // 4 MiB
    float* kf32  = (float*)(ws + 33*PBUF_BYTES + 262144 + 4194304);   // 8 MiB
    float* apow  = (float*)(ws + 33*PBUF_BYTES + 262144 + 4194304 + 8388608); // 2 MiB
    unsigned* cnt = (unsigned*)(ws + 33*PBUF_BYTES + 262144 + 4194304 + 8388608 + 2097152);

    prep1<<<2048, 256, 0, stream>>>(u, B0, Bl, Cst, pall, ccast, kf32, cnt);

    void* args[8] = { (void*)&Ast, (void*)&kf32, (void*)&apow, (void*)&kt,
                      (void*)&pall, (void*)&ccast, (void*)&outp, (void*)&cnt };
    hipLaunchCooperativeKernel((const void*)mega, dim3(NB), dim3(256), args, 0, stream);
}

// Round 2
// 325.755 us; speedup vs baseline: 3.0234x; 3.0234x over previous
//
#include <hip/hip_runtime.h>

// HierarchicalLTI2: 32-layer cascade of 64-dim LTI blocks, T=8192.
// Per-layer FIR truncation at J=16 taps, each layer = GEMM (M=8192,N=64,K=1024)
// via implicit im2col, f16 MFMA fp32-acc.
// R5: launch-bound -> fuse 4 layers per launch (stage4). Each block recomputes
// the intermediate-layer halo in LDS (phases M=80/64/48/32, input halo 96 rows),
// writing each layer's canonical 32 rows to global for y_final.
// 39 dispatches -> 15. Global-barrier persistent kernel (R4) measured
// ~25us/barrier (XCD L2 writeback) -- abandoned.

#define LYR 32
#define NO  64
#define TSEQ 8192
#define JT  16
#define KD  (JT*NO)              // 1024
#define PROWS (TSEQ+JT)          // 8208
#define PBUF ((size_t)PROWS*NO)  // 525312 elements (f16)
#define FD  4                    // fusion depth

typedef _Float16 h16;
typedef _Float16 h16x8 __attribute__((ext_vector_type(8)));
typedef float    f32x4 __attribute__((ext_vector_type(4)));

// ---- prep1: zero pads (all 33 buffers), cast u + C, seed K_0 ---------------
__global__ __launch_bounds__(256) void prep1(
    const float* __restrict__ u, const float* __restrict__ B0,
    const float* __restrict__ Bl, const float* __restrict__ Cst,
    h16* __restrict__ pall, h16* __restrict__ ccast, float* __restrict__ kf32)
{
    int idx = blockIdx.x*256 + threadIdx.x;
    const int n_pad0 = JT*NO;            // 1024
    const int n_u    = TSEQ*NO;          // 524288
    const int n_c    = LYR*NO*NO;        // 131072
    const int n_k    = LYR*NO*NO;        // 131072
    const int n_zp   = 32*JT*NO;         // 32768 (pads of buffers 1..32)
    int total = n_pad0 + n_u + n_c + n_k + n_zp;
    for (; idx < total; idx += gridDim.x*256) {
        int e = idx;
        if (e < n_pad0) { pall[e] = (h16)0.f; continue; }
        e -= n_pad0;
        if (e < n_u) { pall[n_pad0 + e] = (h16)u[e]; continue; }
        e -= n_u;
        if (e < n_c) { ccast[e] = (h16)Cst[e]; continue; }
        e -= n_c;
        if (e < n_k) {
            int i = e >> 12;
            int r = e & 4095;
            kf32[((size_t)i*JT)*4096 + r] = (i == 0) ? B0[r] : Bl[e - 4096];
            continue;
        }
        e -= n_k;
        int b = e >> 10;                 // buffer-1 index 0..31
        int off = e & 1023;
        pall[(size_t)(b+1)*PBUF + off] = (h16)0.f;
    }
}

// ---- build_step: K_{h+q} = A^h * K_q ; A^{2h} = A^h * A^h (s=0..3) ---------
__global__ __launch_bounds__(256) void build_step(
    const float* __restrict__ A_stack, float* __restrict__ kf32,
    float* __restrict__ apow, int s)
{
    int h = 1 << s;
    int extra = (s < 3) ? 1 : 0;
    int slots = h + extra;
    int layer = blockIdx.x / slots;
    int q     = blockIdx.x % slots;
    const float* X = (s == 0) ? (A_stack + (size_t)layer*4096)
                              : (apow + ((size_t)layer*4 + (s-1))*4096);
    const float* Yop;
    float* Z;
    if (q < h) { Yop = kf32 + ((size_t)layer*JT + q)*4096;
                 Z   = kf32 + ((size_t)layer*JT + h + q)*4096; }
    else       { Yop = X;
                 Z   = apow + ((size_t)layer*4 + s)*4096; }

    __shared__ float lx[64*68];
    __shared__ float ly[64*68];
    int tid = threadIdx.x;
    for (int e = tid; e < 4096; e += 256) {
        int r = e >> 6, c = e & 63;
        lx[r*68 + c] = X[e];
        ly[r*68 + c] = Yop[e];
    }
    __syncthreads();
    int r0 = (tid >> 4) << 2;
    int c0 = (tid & 15) << 2;
    float acc[4][4] = {};
    for (int k = 0; k < 64; k++) {
        float a0 = lx[(r0+0)*68 + k];
        float a1 = lx[(r0+1)*68 + k];
        float a2 = lx[(r0+2)*68 + k];
        float a3 = lx[(r0+3)*68 + k];
        f32x4 bv = *(const f32x4*)&ly[k*68 + c0];
        #pragma unroll
        for (int j = 0; j < 4; j++) {
            acc[0][j] += a0*bv[j]; acc[1][j] += a1*bv[j];
            acc[2][j] += a2*bv[j]; acc[3][j] += a3*bv[j];
        }
    }
    #pragma unroll
    for (int i2 = 0; i2 < 4; i2++) {
        f32x4 o; o[0]=acc[i2][0]; o[1]=acc[i2][1]; o[2]=acc[i2][2]; o[3]=acc[i2][3];
        *(f32x4*)&Z[(size_t)(r0+i2)*64 + c0] = o;
    }
}

// ---- castK: Kf32[i][j][n][m] -> f16 KbufT[i][n][(15-j)*64+m] ---------------
__global__ __launch_bounds__(256) void castK(const float* __restrict__ kf32,
                                             h16* __restrict__ kt)
{
    int idx = blockIdx.x*256 + threadIdx.x;
    const int total = LYR*NO*KD;     // 2,097,152
    for (; idx < total; idx += gridDim.x*256) {
        int i   = idx >> 16;
        int rem = idx & 65535;
        int n   = rem >> 10;
        int kap = rem & 1023;
        int jp  = kap >> 6, m = kap & 63;
        int j   = JT-1-jp;
        kt[idx] = (h16)kf32[(((size_t)i*JT + j)*64 + n)*64 + m];
    }
}

// ---- fused-stage phase: GEMM M=16*S, N=64, K=1024, split-K4 ----------------
// inb: LDS input, stride 72, rows >= 16*(S+1). outb: LDS output (stride 72) or
// null for last phase. gout: global base at padded row (t0+16), pitch 64.
// w0: local row where the canonical 32-row window starts.
template<int S>
__device__ __forceinline__ void phase_body(
    const h16* inb, h16* outb, const h16* __restrict__ kb,
    h16* __restrict__ gout, const int w0, float* red, const int tid)
{
    const int wv = tid >> 6, lane = tid & 63, r = lane & 15, q = lane >> 4;
    const h16* abase = inb + (r + wv*4)*72 + q*8;
    const h16* bbase = kb + (size_t)r*KD + wv*256 + q*8;
#define LDA(s, ls) (*(const h16x8*)(abase + ((s)*16 + ((ls)>>1))*72 + ((ls)&1)*32))
#define LDB(c, ls) (*(const h16x8*)(bbase + (c)*(16*KD) + (ls)*32))
    f32x4 acc[S][4] = {};
    h16x8 a0[S], b0[4], a1[S], b1[4];
    #pragma unroll
    for (int s = 0; s < S; s++) { a0[s]=LDA(s,0); a1[s]=LDA(s,1); }
    #pragma unroll
    for (int c = 0; c < 4; c++) { b0[c]=LDB(c,0); b1[c]=LDB(c,1); }
    #pragma unroll 1
    for (int h2 = 0; h2 < 4; h2++) {
        int pE = 2*h2 + 2; pE = pE > 7 ? 7 : pE;
        int pO = 2*h2 + 3; pO = pO > 7 ? 7 : pO;
        h16x8 ca[S], cb[4];
        #pragma unroll
        for (int s = 0; s < S; s++) ca[s] = a0[s];
        #pragma unroll
        for (int c = 0; c < 4; c++) cb[c] = b0[c];
        #pragma unroll
        for (int s = 0; s < S; s++) a0[s] = LDA(s, pE);
        #pragma unroll
        for (int c = 0; c < 4; c++) b0[c] = LDB(c, pE);
        #pragma unroll
        for (int s = 0; s < S; s++)
            #pragma unroll
            for (int c = 0; c < 4; c++)
                acc[s][c] = __builtin_amdgcn_mfma_f32_16x16x32_f16(ca[s], cb[c], acc[s][c], 0,0,0);
        #pragma unroll
        for (int s = 0; s < S; s++) ca[s] = a1[s];
        #pragma unroll
        for (int c = 0; c < 4; c++) cb[c] = b1[c];
        #pragma unroll
        for (int s = 0; s < S; s++) a1[s] = LDA(s, pO);
        #pragma unroll
        for (int c = 0; c < 4; c++) b1[c] = LDB(c, pO);
        #pragma unroll
        for (int s = 0; s < S; s++)
            #pragma unroll
            for (int c = 0; c < 4; c++)
                acc[s][c] = __builtin_amdgcn_mfma_f32_16x16x32_f16(ca[s], cb[c], acc[s][c], 0,0,0);
    }
#undef LDA
#undef LDB
    // split-K reduction + combine, chunked over 2 row-tiles (red = 2 x 32x68 f32)
    const int cb2 = (tid & 7) << 3;
    #pragma unroll
    for (int ch = 0; ch < (S+1)/2; ch++) {
        const int sbase = ch*2;
        const int nt = (S - sbase) < 2 ? (S - sbase) : 2;
        __syncthreads();                 // red free (prev chunk / prev phase done)
        if (wv >= 2) {
            float* myred = red + (size_t)(wv-2)*(32*68);
            #pragma unroll
            for (int s2 = 0; s2 < 2; s2++) if (s2 < nt)
                #pragma unroll
                for (int c = 0; c < 4; c++)
                    #pragma unroll
                    for (int g = 0; g < 4; g++)
                        myred[(s2*16 + q*4 + g)*68 + c*16 + r] = acc[sbase+s2][c][g];
        }
        __syncthreads();
        if (wv < 2) {
            float* myred = red + (size_t)wv*(32*68);
            #pragma unroll
            for (int s2 = 0; s2 < 2; s2++) if (s2 < nt)
                #pragma unroll
                for (int c = 0; c < 4; c++)
                    #pragma unroll
                    for (int g = 0; g < 4; g++)
                        myred[(s2*16 + q*4 + g)*68 + c*16 + r] += acc[sbase+s2][c][g];
        }
        __syncthreads();
        for (int w = tid >> 3; w < nt*16; w += 32) {
            f32x4 u0 = *(const f32x4*)&red[w*68 + cb2];
            f32x4 u1 = *(const f32x4*)&red[w*68 + cb2 + 4];
            f32x4 v0 = *(const f32x4*)&red[32*68 + w*68 + cb2];
            f32x4 v1 = *(const f32x4*)&red[32*68 + w*68 + cb2 + 4];
            u0 += v0; u1 += v1;
            h16 ov[8];
            #pragma unroll
            for (int j = 0; j < 4; j++) { ov[j] = (h16)u0[j]; ov[4+j] = (h16)u1[j]; }
            const int W = sbase*16 + w;          // global-phase row
            if (outb) *(int4*)&outb[W*72 + cb2] = *(int4*)&ov[0];
            const unsigned wrel = (unsigned)(W - w0);
            if (wrel < 32u) *(int4*)&gout[(size_t)wrel*64 + cb2] = *(int4*)&ov[0];
        }
    }
    __syncthreads();                     // outb ready for next phase
}

// ---- stage4: 4 fused cascade layers, one 32-row output tile per block ------
__global__ __launch_bounds__(256) void stage4(
    h16* pall, const h16* __restrict__ kt, int i0)
{
    __shared__ __align__(16) h16   bufA[96*72];      // 13,824 B
    __shared__ __align__(16) h16   bufB[96*72];      // 13,824 B
    __shared__ __align__(16) float red[2*32*68];     // 17,408 B
    const int tid = threadIdx.x;
    const size_t t0 = (size_t)blockIdx.x * 32;

    // stage input halo: 96 rows = padded rows t0-48 .. t0+47 of buffer i0
    const h16* pin = pall + (size_t)i0*PBUF;
    for (int e = tid; e < 96*8; e += 256) {
        int rr = e >> 3, cc = e & 7;
        long g = (long)t0 - 48 + rr;
        int4 v = make_int4(0,0,0,0);
        if (g >= 0) v = *(const int4*)&pin[(size_t)g*64 + cc*8];
        *(int4*)&bufA[rr*72 + cc*8] = v;
    }
    __syncthreads();

    h16* g1 = pall + (size_t)(i0+1)*PBUF + (JT + t0)*64;
    h16* g2 = pall + (size_t)(i0+2)*PBUF + (JT + t0)*64;
    h16* g3 = pall + (size_t)(i0+3)*PBUF + (JT + t0)*64;
    h16* g4 = pall + (size_t)(i0+4)*PBUF + (JT + t0)*64;
    const h16* k1 = kt + (size_t)(i0+0)*NO*KD;
    const h16* k2 = kt + (size_t)(i0+1)*NO*KD;
    const h16* k3 = kt + (size_t)(i0+2)*NO*KD;
    const h16* k4 = kt + (size_t)(i0+3)*NO*KD;

    phase_body<5>(bufA, bufB, k1, g1, 48, red, tid);   // layer i0+1: M=80
    phase_body<4>(bufB, bufA, k2, g2, 32, red, tid);   // layer i0+2: M=64
    phase_body<3>(bufA, bufB, k3, g3, 16, red, tid);   // layer i0+3: M=48
    phase_body<2>(bufB, (h16*)0, k4, g4, 0, red, tid); // layer i0+4: M=32
}

// ---- y_final: Y = sum_i X^(i) C_i^T, 32-row tiles, split-K4 ----------------
__global__ __launch_bounds__(256, 2) void y_final(
    const h16* __restrict__ pall, const h16* __restrict__ ccast,
    float* __restrict__ out)
{
    __shared__ __align__(16) float red[2*32*68];
    int tid = threadIdx.x;
    size_t t0 = (size_t)blockIdx.x * 32;
    int wv = tid >> 6, lane = tid & 63, r = lane & 15, q = lane >> 4;
    const h16* abase = pall + (size_t)(wv*8 + 1)*PBUF + (JT + t0 + r)*64 + q*8;
    const h16* bbase = ccast + (size_t)(wv*8)*4096 + (size_t)r*64 + q*8;
#define LDA2(s, ls) (*(const h16x8*)(abase + (size_t)((ls)>>1)*PBUF + (s)*(16*64) + ((ls)&1)*32))
#define LDB2(c, ls) (*(const h16x8*)(bbase + ((ls)>>1)*4096 + (c)*(16*64) + ((ls)&1)*32))
    f32x4 acc[2][4] = {};
    h16x8 a0[2], b0[4], a1[2], b1[4];
    #pragma unroll
    for (int s = 0; s < 2; s++) { a0[s]=LDA2(s,0); a1[s]=LDA2(s,1); }
    #pragma unroll
    for (int c = 0; c < 4; c++) { b0[c]=LDB2(c,0); b1[c]=LDB2(c,1); }
    #pragma unroll 1
    for (int h2 = 0; h2 < 8; h2++) {
        int pE = 2*h2 + 2; pE = pE > 15 ? 15 : pE;
        int pO = 2*h2 + 3; pO = pO > 15 ? 15 : pO;
        h16x8 ca[2], cb[4];
        #pragma unroll
        for (int s = 0; s < 2; s++) ca[s] = a0[s];
        #pragma unroll
        for (int c = 0; c < 4; c++) cb[c] = b0[c];
        #pragma unroll
        for (int s = 0; s < 2; s++) a0[s] = LDA2(s, pE);
        #pragma unroll
        for (int c = 0; c < 4; c++) b0[c] = LDB2(c, pE);
        #pragma unroll
        for (int s = 0; s < 2; s++)
            #pragma unroll
            for (int c = 0; c < 4; c++)
                acc[s][c] = __builtin_amdgcn_mfma_f32_16x16x32_f16(ca[s], cb[c], acc[s][c], 0,0,0);
        #pragma unroll
        for (int s = 0; s < 2; s++) ca[s] = a1[s];
        #pragma unroll
        for (int c = 0; c < 4; c++) cb[c] = b1[c];
        #pragma unroll
        for (int s = 0; s < 2; s++) a1[s] = LDA2(s, pO);
        #pragma unroll
        for (int c = 0; c < 4; c++) b1[c] = LDB2(c, pO);
        #pragma unroll
        for (int s = 0; s < 2; s++)
            #pragma unroll
            for (int c = 0; c < 4; c++)
                acc[s][c] = __builtin_amdgcn_mfma_f32_16x16x32_f16(ca[s], cb[c], acc[s][c], 0,0,0);
    }
#undef LDA2
#undef LDB2
    if (wv >= 2) {
        float* myred = red + (size_t)(wv-2)*(32*68);
        #pragma unroll
        for (int s = 0; s < 2; s++)
            #pragma unroll
            for (int c = 0; c < 4; c++)
                #pragma unroll
                for (int g = 0; g < 4; g++)
                    myred[(s*16 + q*4 + g)*68 + c*16 + r] = acc[s][c][g];
    }
    __syncthreads();
    if (wv < 2) {
        float* myred = red + (size_t)wv*(32*68);
        #pragma unroll
        for (int s = 0; s < 2; s++)
            #pragma unroll
            for (int c = 0; c < 4; c++)
                #pragma unroll
                for (int g = 0; g < 4; g++)
                    myred[(s*16 + q*4 + g)*68 + c*16 + r] += acc[s][c][g];
    }
    __syncthreads();
    int orow = tid >> 3, cb2 = (tid & 7) << 3;
    f32x4 u0 = *(const f32x4*)&red[orow*68 + cb2];
    f32x4 u1 = *(const f32x4*)&red[orow*68 + cb2 + 4];
    f32x4 v0 = *(const f32x4*)&red[32*68 + orow*68 + cb2];
    f32x4 v1 = *(const f32x4*)&red[32*68 + orow*68 + cb2 + 4];
    u0 += v0; u1 += v1;
    size_t obase = (t0 + orow)*64 + cb2;
    *(f32x4*)&out[obase]     = u0;
    *(f32x4*)&out[obase + 4] = u1;
}

extern "C" void kernel_launch(void* const* d_in, const int* in_sizes, int n_in,
                              void* d_out, int out_size, void* d_ws, size_t ws_size,
                              hipStream_t stream)
{
    const float* u   = (const float*)d_in[0];
    const float* Ast = (const float*)d_in[1];
    const float* B0  = (const float*)d_in[2];
    const float* Bl  = (const float*)d_in[3];
    const float* Cst = (const float*)d_in[4];
    float* out = (float*)d_out;
    (void)in_sizes; (void)n_in; (void)out_size; (void)ws_size;

    char* ws = (char*)d_ws;
    const size_t PBUF_BYTES = PBUF*sizeof(h16);            // 1,050,624
    h16*   pall  = (h16*)ws;                               // 33 buffers
    h16*   ccast = (h16*)(ws + 33*PBUF_BYTES);             // 256 KiB
    h16*   kt    = (h16*)(ws + 33*PBUF_BYTES + 262144);    // 4 MiB
    float* kf32  = (float*)(ws + 33*PBUF_BYTES + 262144 + 4194304);   // 8 MiB
    float* apow  = (float*)(ws + 33*PBUF_BYTES + 262144 + 4194304 + 8388608); // 2 MiB

    prep1<<<2048, 256, 0, stream>>>(u, B0, Bl, Cst, pall, ccast, kf32);
    for (int s = 0; s < 4; s++) {
        int h = 1 << s;
        int grid = 32*(h + (s < 3 ? 1 : 0));
        build_step<<<grid, 256, 0, stream>>>(Ast, kf32, apow, s);
    }
    castK<<<2048, 256, 0, stream>>>(kf32, kt);
    for (int i = 0; i < LYR; i += FD) {
        stage4<<<TSEQ/32, 256, 0, stream>>>(pall, kt, i);
    }
    y_final<<<TSEQ/32, 256, 0, stream>>>(pall, ccast, out);
}

// Round 4
// 306.872 us; speedup vs baseline: 3.2094x; 1.0615x over previous
//
#include <hip/hip_runtime.h>

// HierarchicalLTI2: 32-layer cascade of 64-dim LTI blocks, T=8192.
// Per-layer FIR truncation at J=16 taps, each layer = GEMM (M=8192,N=64,K=1024)
// via implicit im2col, f16 MFMA fp32-acc.
// R6 (resubmit; prior run died to container infra, kernel never measured):
// stages measured ~280 TF effective -- B-frags come from global (L2) with
// only 2-half-step prefetch (~80cy) vs ~250cy L2 latency at 1 block/CU.
// -> 4-deep B prefetch (+4-deep A/B in y_final), 3-tile reduction chunks,
// vectorized prep1/castK. Structure otherwise identical to verified R5.

#define LYR 32
#define NO  64
#define TSEQ 8192
#define JT  16
#define KD  (JT*NO)              // 1024
#define PROWS (TSEQ+JT)          // 8208
#define PBUF ((size_t)PROWS*NO)  // 525312 elements (f16)
#define FD  4                    // fusion depth

typedef _Float16 h16;
typedef _Float16 h16x8 __attribute__((ext_vector_type(8)));
typedef float    f32x4 __attribute__((ext_vector_type(4)));

// ---- prep1: zero pads (all 33 buffers), cast u + C, seed K_0 (vectorized x8)
__global__ __launch_bounds__(256) void prep1(
    const float* __restrict__ u, const float* __restrict__ B0,
    const float* __restrict__ Bl, const float* __restrict__ Cst,
    h16* __restrict__ pall, h16* __restrict__ ccast, float* __restrict__ kf32)
{
    const int n_pad0 = JT*NO;            // 1024
    const int n_u    = TSEQ*NO;          // 524288
    const int n_c    = LYR*NO*NO;        // 131072
    const int n_k    = LYR*NO*NO;        // 131072
    const int n_zp   = 32*JT*NO;         // 32768 (pads of buffers 1..32)
    const int total8 = (n_pad0 + n_u + n_c + n_k + n_zp) >> 3;
    int idx8 = blockIdx.x*256 + threadIdx.x;
    const int4 zero4 = make_int4(0,0,0,0);
    for (; idx8 < total8; idx8 += gridDim.x*256) {
        int e = idx8 << 3;
        if (e < n_pad0) { *(int4*)&pall[e] = zero4; continue; }
        e -= n_pad0;
        if (e < n_u) {
            f32x4 f0 = *(const f32x4*)&u[e];
            f32x4 f1 = *(const f32x4*)&u[e+4];
            h16 ov[8];
            #pragma unroll
            for (int j = 0; j < 4; j++) { ov[j] = (h16)f0[j]; ov[4+j] = (h16)f1[j]; }
            *(int4*)&pall[n_pad0 + e] = *(int4*)&ov[0];
            continue;
        }
        e -= n_u;
        if (e < n_c) {
            f32x4 f0 = *(const f32x4*)&Cst[e];
            f32x4 f1 = *(const f32x4*)&Cst[e+4];
            h16 ov[8];
            #pragma unroll
            for (int j = 0; j < 4; j++) { ov[j] = (h16)f0[j]; ov[4+j] = (h16)f1[j]; }
            *(int4*)&ccast[e] = *(int4*)&ov[0];
            continue;
        }
        e -= n_c;
        if (e < n_k) {
            int i = e >> 12;
            int r = e & 4095;
            const float* src = (i == 0) ? &B0[r] : &Bl[e - 4096];
            float* dst = &kf32[((size_t)i*JT)*4096 + r];
            *(f32x4*)&dst[0] = *(const f32x4*)&src[0];
            *(f32x4*)&dst[4] = *(const f32x4*)&src[4];
            continue;
        }
        e -= n_k;
        int b = e >> 10;                 // buffer-1 index 0..31
        int off = e & 1023;
        *(int4*)&pall[(size_t)(b+1)*PBUF + off] = zero4;
    }
}

// ---- build_step: K_{h+q} = A^h * K_q ; A^{2h} = A^h * A^h (s=0..3) ---------
__global__ __launch_bounds__(256) void build_step(
    const float* __restrict__ A_stack, float* __restrict__ kf32,
    float* __restrict__ apow, int s)
{
    int h = 1 << s;
    int extra = (s < 3) ? 1 : 0;
    int slots = h + extra;
    int layer = blockIdx.x / slots;
    int q     = blockIdx.x % slots;
    const float* X = (s == 0) ? (A_stack + (size_t)layer*4096)
                              : (apow + ((size_t)layer*4 + (s-1))*4096);
    const float* Yop;
    float* Z;
    if (q < h) { Yop = kf32 + ((size_t)layer*JT + q)*4096;
                 Z   = kf32 + ((size_t)layer*JT + h + q)*4096; }
    else       { Yop = X;
                 Z   = apow + ((size_t)layer*4 + s)*4096; }

    __shared__ float lx[64*68];
    __shared__ float ly[64*68];
    int tid = threadIdx.x;
    for (int e = tid; e < 4096; e += 256) {
        int r = e >> 6, c = e & 63;
        lx[r*68 + c] = X[e];
        ly[r*68 + c] = Yop[e];
    }
    __syncthreads();
    int r0 = (tid >> 4) << 2;
    int c0 = (tid & 15) << 2;
    float acc[4][4] = {};
    for (int k = 0; k < 64; k++) {
        float a0 = lx[(r0+0)*68 + k];
        float a1 = lx[(r0+1)*68 + k];
        float a2 = lx[(r0+2)*68 + k];
        float a3 = lx[(r0+3)*68 + k];
        f32x4 bv = *(const f32x4*)&ly[k*68 + c0];
        #pragma unroll
        for (int j = 0; j < 4; j++) {
            acc[0][j] += a0*bv[j]; acc[1][j] += a1*bv[j];
            acc[2][j] += a2*bv[j]; acc[3][j] += a3*bv[j];
        }
    }
    #pragma unroll
    for (int i2 = 0; i2 < 4; i2++) {
        f32x4 o; o[0]=acc[i2][0]; o[1]=acc[i2][1]; o[2]=acc[i2][2]; o[3]=acc[i2][3];
        *(f32x4*)&Z[(size_t)(r0+i2)*64 + c0] = o;
    }
}

// ---- castK: Kf32[i][j][n][m] -> f16 KbufT[i][n][(15-j)*64+m] (vectorized x4)
__global__ __launch_bounds__(256) void castK(const float* __restrict__ kf32,
                                             h16* __restrict__ kt)
{
    int idx4 = blockIdx.x*256 + threadIdx.x;
    const int total4 = (LYR*NO*KD) >> 2;     // 524,288
    for (; idx4 < total4; idx4 += gridDim.x*256) {
        int idx = idx4 << 2;
        int i   = idx >> 16;
        int rem = idx & 65535;
        int n   = rem >> 10;
        int kap = rem & 1023;
        int jp  = kap >> 6, m = kap & 63;
        int j   = JT-1-jp;
        f32x4 f = *(const f32x4*)&kf32[(((size_t)i*JT + j)*64 + n)*64 + m];
        h16 ov[4];
        #pragma unroll
        for (int t = 0; t < 4; t++) ov[t] = (h16)f[t];
        *(int2*)&kt[idx] = *(int2*)&ov[0];
    }
}

// ---- fused-stage phase: GEMM M=16*S, N=64, K=1024, split-K4 ----------------
// inb: LDS input, stride 72, rows >= 16*(S+1). outb: LDS output (stride 72) or
// null for last phase. gout: global base at padded row (t0+16), pitch 64.
// w0: local row where the canonical 32-row window starts.
// B-frags (global kt) prefetched 4 half-steps deep; A-frags (LDS) 2 deep.
template<int S>
__device__ __forceinline__ void phase_body(
    const h16* inb, h16* outb, const h16* __restrict__ kb,
    h16* __restrict__ gout, const int w0, float* red, const int tid)
{
    const int wv = tid >> 6, lane = tid & 63, r = lane & 15, q = lane >> 4;
    const h16* abase = inb + (r + wv*4)*72 + q*8;
    const h16* bbase = kb + (size_t)r*KD + wv*256 + q*8;
#define LDA(s, ls) (*(const h16x8*)(abase + ((s)*16 + ((ls)>>1))*72 + ((ls)&1)*32))
#define LDB(c, ls) (*(const h16x8*)(bbase + (c)*(16*KD) + (ls)*32))
    f32x4 acc[S][4] = {};
    h16x8 a[2][S], b[4][4];
    #pragma unroll
    for (int ls = 0; ls < 2; ls++)
        #pragma unroll
        for (int s = 0; s < S; s++) a[ls][s] = LDA(s, ls);
    #pragma unroll
    for (int ls = 0; ls < 4; ls++)
        #pragma unroll
        for (int c = 0; c < 4; c++) b[ls][c] = LDB(c, ls);
    #pragma unroll
    for (int ls = 0; ls < 8; ls++) {
        h16x8 ca[S], cb[4];
        #pragma unroll
        for (int s = 0; s < S; s++) ca[s] = a[ls&1][s];
        #pragma unroll
        for (int c = 0; c < 4; c++) cb[c] = b[ls&3][c];
        if (ls < 6) {
            #pragma unroll
            for (int s = 0; s < S; s++) a[ls&1][s] = LDA(s, ls+2);
        }
        if (ls < 4) {
            #pragma unroll
            for (int c = 0; c < 4; c++) b[ls&3][c] = LDB(c, ls+4);
        }
        #pragma unroll
        for (int s = 0; s < S; s++)
            #pragma unroll
            for (int c = 0; c < 4; c++)
                acc[s][c] = __builtin_amdgcn_mfma_f32_16x16x32_f16(ca[s], cb[c], acc[s][c], 0,0,0);
    }
#undef LDA
#undef LDB
    // split-K reduction + combine, chunked over 3 row-tiles (red = 2 x 48x68 f32)
    const int cb2 = (tid & 7) << 3;
    #pragma unroll
    for (int ch = 0; ch < (S+2)/3; ch++) {
        const int sbase = ch*3;
        const int nt = (S - sbase) < 3 ? (S - sbase) : 3;
        __syncthreads();                 // red free (prev chunk / prev phase done)
        if (wv >= 2) {
            float* myred = red + (size_t)(wv-2)*(48*68);
            #pragma unroll
            for (int s2 = 0; s2 < 3; s2++) if (s2 < nt)
                #pragma unroll
                for (int c = 0; c < 4; c++)
                    #pragma unroll
                    for (int g = 0; g < 4; g++)
                        myred[(s2*16 + q*4 + g)*68 + c*16 + r] = acc[sbase+s2][c][g];
        }
        __syncthreads();
        if (wv < 2) {
            float* myred = red + (size_t)wv*(48*68);
            #pragma unroll
            for (int s2 = 0; s2 < 3; s2++) if (s2 < nt)
                #pragma unroll
                for (int c = 0; c < 4; c++)
                    #pragma unroll
                    for (int g = 0; g < 4; g++)
                        myred[(s2*16 + q*4 + g)*68 + c*16 + r] += acc[sbase+s2][c][g];
        }
        __syncthreads();
        for (int w = tid >> 3; w < nt*16; w += 32) {
            f32x4 u0 = *(const f32x4*)&red[w*68 + cb2];
            f32x4 u1 = *(const f32x4*)&red[w*68 + cb2 + 4];
            f32x4 v0 = *(const f32x4*)&red[48*68 + w*68 + cb2];
            f32x4 v1 = *(const f32x4*)&red[48*68 + w*68 + cb2 + 4];
            u0 += v0; u1 += v1;
            h16 ov[8];
            #pragma unroll
            for (int j = 0; j < 4; j++) { ov[j] = (h16)u0[j]; ov[4+j] = (h16)u1[j]; }
            const int W = sbase*16 + w;          // global-phase row
            if (outb) *(int4*)&outb[W*72 + cb2] = *(int4*)&ov[0];
            const unsigned wrel = (unsigned)(W - w0);
            if (wrel < 32u) *(int4*)&gout[(size_t)wrel*64 + cb2] = *(int4*)&ov[0];
        }
    }
    __syncthreads();                     // outb ready for next phase
}

// ---- stage4: 4 fused cascade layers, one 32-row output tile per block ------
__global__ __launch_bounds__(256) void stage4(
    h16* pall, const h16* __restrict__ kt, int i0)
{
    __shared__ __align__(16) h16   bufA[96*72];      // 13,824 B
    __shared__ __align__(16) h16   bufB[96*72];      // 13,824 B
    __shared__ __align__(16) float red[2*48*68];     // 26,112 B
    const int tid = threadIdx.x;
    const size_t t0 = (size_t)blockIdx.x * 32;

    // stage input halo: 96 rows = padded rows t0-48 .. t0+47 of buffer i0
    const h16* pin = pall + (size_t)i0*PBUF;
    for (int e = tid; e < 96*8; e += 256) {
        int rr = e >> 3, cc = e & 7;
        long g = (long)t0 - 48 + rr;
        int4 v = make_int4(0,0,0,0);
        if (g >= 0) v = *(const int4*)&pin[(size_t)g*64 + cc*8];
        *(int4*)&bufA[rr*72 + cc*8] = v;
    }
    __syncthreads();

    h16* g1 = pall + (size_t)(i0+1)*PBUF + (JT + t0)*64;
    h16* g2 = pall + (size_t)(i0+2)*PBUF + (JT + t0)*64;
    h16* g3 = pall + (size_t)(i0+3)*PBUF + (JT + t0)*64;
    h16* g4 = pall + (size_t)(i0+4)*PBUF + (JT + t0)*64;
    const h16* k1 = kt + (size_t)(i0+0)*NO*KD;
    const h16* k2 = kt + (size_t)(i0+1)*NO*KD;
    const h16* k3 = kt + (size_t)(i0+2)*NO*KD;
    const h16* k4 = kt + (size_t)(i0+3)*NO*KD;

    phase_body<5>(bufA, bufB, k1, g1, 48, red, tid);   // layer i0+1: M=80
    phase_body<4>(bufB, bufA, k2, g2, 32, red, tid);   // layer i0+2: M=64
    phase_body<3>(bufA, bufB, k3, g3, 16, red, tid);   // layer i0+3: M=48
    phase_body<2>(bufB, (h16*)0, k4, g4, 0, red, tid); // layer i0+4: M=32
}

// ---- y_final: Y = sum_i X^(i) C_i^T, 32-row tiles, split-K4, 4-deep pf -----
__global__ __launch_bounds__(256, 2) void y_final(
    const h16* __restrict__ pall, const h16* __restrict__ ccast,
    float* __restrict__ out)
{
    __shared__ __align__(16) float red[2*32*68];
    int tid = threadIdx.x;
    size_t t0 = (size_t)blockIdx.x * 32;
    int wv = tid >> 6, lane = tid & 63, r = lane & 15, q = lane >> 4;
    // wave wv owns layers i in [wv*8, wv*8+8): 16 half-steps of 32 K-elems
    const h16* abase = pall + (size_t)(wv*8 + 1)*PBUF + (JT + t0 + r)*64 + q*8;
    const h16* bbase = ccast + (size_t)(wv*8)*4096 + (size_t)r*64 + q*8;
#define LDA2(s, ls) (*(const h16x8*)(abase + (size_t)((ls)>>1)*PBUF + (s)*(16*64) + ((ls)&1)*32))
#define LDB2(c, ls) (*(const h16x8*)(bbase + ((ls)>>1)*4096 + (c)*(16*64) + ((ls)&1)*32))
    f32x4 acc[2][4] = {};
    h16x8 a[4][2], b[4][4];
    #pragma unroll
    for (int ls = 0; ls < 4; ls++) {
        #pragma unroll
        for (int s = 0; s < 2; s++) a[ls][s] = LDA2(s, ls);
        #pragma unroll
        for (int c = 0; c < 4; c++) b[ls][c] = LDB2(c, ls);
    }
    #pragma unroll
    for (int ls = 0; ls < 16; ls++) {
        h16x8 ca[2], cb[4];
        #pragma unroll
        for (int s = 0; s < 2; s++) ca[s] = a[ls&3][s];
        #pragma unroll
        for (int c = 0; c < 4; c++) cb[c] = b[ls&3][c];
        if (ls < 12) {
            #pragma unroll
            for (int s = 0; s < 2; s++) a[ls&3][s] = LDA2(s, ls+4);
            #pragma unroll
            for (int c = 0; c < 4; c++) b[ls&3][c] = LDB2(c, ls+4);
        }
        #pragma unroll
        for (int s = 0; s < 2; s++)
            #pragma unroll
            for (int c = 0; c < 4; c++)
                acc[s][c] = __builtin_amdgcn_mfma_f32_16x16x32_f16(ca[s], cb[c], acc[s][c], 0,0,0);
    }
#undef LDA2
#undef LDB2
    if (wv >= 2) {
        float* myred = red + (size_t)(wv-2)*(32*68);
        #pragma unroll
        for (int s = 0; s < 2; s++)
            #pragma unroll
            for (int c = 0; c < 4; c++)
                #pragma unroll
                for (int g = 0; g < 4; g++)
                    myred[(s*16 + q*4 + g)*68 + c*16 + r] = acc[s][c][g];
    }
    __syncthreads();
    if (wv < 2) {
        float* myred = red + (size_t)wv*(32*68);
        #pragma unroll
        for (int s = 0; s < 2; s++)
            #pragma unroll
            for (int c = 0; c < 4; c++)
                #pragma unroll
                for (int g = 0; g < 4; g++)
                    myred[(s*16 + q*4 + g)*68 + c*16 + r] += acc[s][c][g];
    }
    __syncthreads();
    int orow = tid >> 3, cb2 = (tid & 7) << 3;
    f32x4 u0 = *(const f32x4*)&red[orow*68 + cb2];
    f32x4 u1 = *(const f32x4*)&red[orow*68 + cb2 + 4];
    f32x4 v0 = *(const f32x4*)&red[32*68 + orow*68 + cb2];
    f32x4 v1 = *(const f32x4*)&red[32*68 + orow*68 + cb2 + 4];
    u0 += v0; u1 += v1;
    size_t obase = (t0 + orow)*64 + cb2;
    *(f32x4*)&out[obase]     = u0;
    *(f32x4*)&out[obase + 4] = u1;
}

extern "C" void kernel_launch(void* const* d_in, const int* in_sizes, int n_in,
                              void* d_out, int out_size, void* d_ws, size_t ws_size,
                              hipStream_t stream)
{
    const float* u   = (const float*)d_in[0];
    const float* Ast = (const float*)d_in[1];
    const float* B0  = (const float*)d_in[2];
    const float* Bl  = (const float*)d_in[3];
    const float* Cst = (const float*)d_in[4];
    float* out = (float*)d_out;
    (void)in_sizes; (void)n_in; (void)out_size; (void)ws_size;

    char* ws = (char*)d_ws;
    const size_t PBUF_BYTES = PBUF*sizeof(h16);            // 1,050,624
    h16*   pall  = (h16*)ws;                               // 33 buffers
    h16*   ccast = (h16*)(ws + 33*PBUF_BYTES);             // 256 KiB
    h16*   kt    = (h16*)(ws + 33*PBUF_BYTES + 262144);    // 4 MiB
    float* kf32  = (float*)(ws + 33*PBUF_BYTES + 262144 + 4194304);   // 8 MiB
    float* apow  = (float*)(ws + 33*PBUF_BYTES + 262144 + 4194304 + 8388608); // 2 MiB

    prep1<<<512, 256, 0, stream>>>(u, B0, Bl, Cst, pall, ccast, kf32);
    for (int s = 0; s < 4; s++) {
        int h = 1 << s;
        int grid = 32*(h + (s < 3 ? 1 : 0));
        build_step<<<grid, 256, 0, stream>>>(Ast, kf32, apow, s);
    }
    castK<<<2048, 256, 0, stream>>>(kf32, kt);
    for (int i = 0; i < LYR; i += FD) {
        stage4<<<TSEQ/32, 256, 0, stream>>>(pall, kt, i);
    }
    y_final<<<TSEQ/32, 256, 0, stream>>>(pall, ccast, out);
}